// Round 6
// baseline (91.808 us; speedup 1.0000x reference)
//
#include <hip/hip_runtime.h>
#include <math.h>

#define BM 60      // modes per batch
#define TT 80      // timesteps
#define NAG 128    // agents
#define NLANES 64
#define NPTS 20
#define NLP (NLANES * NPTS)  // 1280 lane points
#define APL (NAG / 64)       // 2 agents per lane
#define J 10                 // timesteps per tile
#define BIGOFF 1e8f

// Fused kernel: block bm computes score(b,m); the last block of each batch
// (device-scope fan-in via counters[b]) does softmax+argmax+output copy.
// Lane points live in LDS SoA (stride-1 across lanes: conflict-free);
// per-lane live registers ~50 (no spill). Distance expansion:
//   d^2 = c_t + s, s = q_p - 2 ex px - 2 ey py, q_p = px^2+py^2 + (1-mask)*1e8
// (mask folded into q; booleans match the reference's +1e6 distance penalty).
__global__ __launch_bounds__(256) void fused_kernel(
    const float* __restrict__ logits,  // (B, M)
    const float* __restrict__ trajs,   // (B, M, T, 3)
    const float* __restrict__ agents,  // (B, NAG, 4)
    const float* __restrict__ amask,   // (B, NAG)
    const float* __restrict__ lanes,   // (B, NLANES, NPTS, 3)
    const float* __restrict__ lmask,   // (B, NLANES)
    int*   __restrict__ counters,      // (B,), zeroed before launch
    float* __restrict__ scores,        // (B*M,) scratch
    float* __restrict__ out,           // traj (B*T*3) then idx (B)
    int B)
{
    __shared__ float s_px[NLP], s_py[NLP], s_pq[NLP];
    __shared__ float s_ex[TT], s_ey[TT];
    __shared__ float s_lm[NLANES];
    __shared__ float s_j[2];
    __shared__ float s_cc[4], s_cd[4];
    __shared__ int   s_sel;
    __shared__ int   s_idx;

    const int bm   = blockIdx.x;   // b*M + m
    const int b    = bm / BM;
    const int tid  = threadIdx.x;  // 0..255
    const int w    = tid >> 6;     // wave 0..3
    const int lane = tid & 63;

    // ---- staging: coalesced float4 reads, scatter to LDS SoA (drop z) ----
    const float4* gl4 = (const float4*)(lanes + (size_t)b * NLP * 3);
    for (int g = tid; g < (NLP * 3) / 4; g += 256) {
        const float4 v = gl4[g];
        const float vv[4] = {v.x, v.y, v.z, v.w};
#pragma unroll
        for (int c = 0; c < 4; ++c) {
            const int f = 4 * g + c;
            const int p = f / 3;
            const int r = f - 3 * p;
            if (r == 0)      s_px[p] = vv[c];
            else if (r == 1) s_py[p] = vv[c];
        }
    }
    if (tid < (TT * 3) / 4) {
        const float4 v = ((const float4*)(trajs + (size_t)bm * TT * 3))[tid];
        const float vv[4] = {v.x, v.y, v.z, v.w};
#pragma unroll
        for (int c = 0; c < 4; ++c) {
            const int f = 4 * tid + c;
            const int t = f / 3;
            const int r = f - 3 * t;
            if (r == 0)      s_ex[t] = vv[c];
            else if (r == 1) s_ey[t] = vv[c];
        }
    }
    if (tid < NLANES) s_lm[tid] = lmask[b * NLANES + tid];

    // agents: 16-byte records -> registers (only 6 regs)
    float ax[APL], ay[APL], aq[APL];
    const float4* ga4 = (const float4*)(agents + (size_t)b * NAG * 4);
#pragma unroll
    for (int k = 0; k < APL; ++k) {
        const int i = k * 64 + lane;
        const float4 a = ga4[i];
        const float mo = (1.0f - amask[b * NAG + i]) * BIGOFF;
        ax[k] = a.x; ay[k] = a.y;
        aq[k] = fmaf(a.x, a.x, a.y * a.y) + mo;
    }
    __syncthreads();

    // q for lane points (reads s_px/s_py written before the barrier)
    for (int p = tid; p < NLP; p += 256) {
        const float x = s_px[p], y = s_py[p];
        const float mo = (1.0f - s_lm[p / NPTS]) * BIGOFF;
        s_pq[p] = fmaf(x, x, y * y) + mo;
    }

    // comfort: jerk[t] = x[t+3]-3x[t+2]+3x[t+1]-x[t], t in [0,77)
    float jsum = 0.0f;
    if (tid < TT - 3) {
        const float jx = s_ex[tid + 3] - 3.0f * s_ex[tid + 2] + 3.0f * s_ex[tid + 1] - s_ex[tid];
        const float jy = s_ey[tid + 3] - 3.0f * s_ey[tid + 2] + 3.0f * s_ey[tid + 1] - s_ey[tid];
        jsum = sqrtf(jx * jx + jy * jy);
    }
    for (int off = 32; off > 0; off >>= 1) jsum += __shfl_xor(jsum, off, 64);
    if (w < 2 && lane == 0) s_j[w] = jsum;
    __syncthreads();  // s_pq + s_j complete

    // ---- hot loop: wave w owns t in [20w, 20w+20), 2 tiles of J=10 ----
    int ccoll = 0, cdriv = 0;
    const int t0 = w * (TT / 4);
    for (int rr = 0; rr < 2; ++rr) {
        const int tb = t0 + rr * J;
        float mx[J], my[J], mA[J], mB[J];
#pragma unroll
        for (int j = 0; j < J; ++j) {
            const float ex = s_ex[tb + j];   // broadcast read
            const float ey = s_ey[tb + j];
            mx[j] = -2.0f * ex;
            my[j] = -2.0f * ey;
            mA[j] = 1e30f;
            mB[j] = 1e30f;
        }
#pragma unroll
        for (int k = 0; k < APL; ++k) {
#pragma unroll
            for (int j = 0; j < J; ++j) {
                float v = fmaf(my[j], ay[k], aq[k]);
                v = fmaf(mx[j], ax[k], v);
                mA[j] = fminf(mA[j], v);
            }
        }
        for (int k = 0; k < NLP / 64; ++k) {
            const int p = k * 64 + lane;
            const float x = s_px[p], y = s_py[p], q = s_pq[p];
#pragma unroll
            for (int j = 0; j < J; ++j) {
                float v = fmaf(my[j], y, q);
                v = fmaf(mx[j], x, v);
                mB[j] = fminf(mB[j], v);
            }
        }
#pragma unroll
        for (int j = 0; j < J; ++j) {
            const float ex = s_ex[tb + j], ey = s_ey[tb + j];
            const float c = fmaf(ex, ex, ey * ey);
            // min d^2 < 4 <=> exists s < 4-c ; min d^2 > 9 <=> no s <= 9-c
            ccoll += (__ballot(mA[j] < 4.0f - c) != 0ull) ? 1 : 0;
            cdriv += (__ballot(mB[j] <= 9.0f - c) == 0ull) ? 1 : 0;
        }
    }
    if (lane == 0) { s_cc[w] = (float)ccoll; s_cd[w] = (float)cdriv; }
    __syncthreads();

    if (tid == 0) {
        const float coll = s_cc[0] + s_cc[1] + s_cc[2] + s_cc[3];
        const float driv = s_cd[0] + s_cd[1] + s_cd[2] + s_cd[3];
        const float comfort  = -((s_j[0] + s_j[1]) / (float)(TT - 3));
        const float progress = s_ex[TT - 1];
        scores[bm] = 0.1f * comfort + 0.5f * progress
                   - 1.0f * (coll / (float)TT)
                   - 0.3f * (driv / (float)TT);
        __threadfence();                        // release: score visible device-wide
        const int old = atomicAdd(&counters[b], 1);  // device-scope
        s_sel = (old == BM - 1) ? 1 : 0;
    }
    __syncthreads();
    if (!s_sel) return;

    // ---- selection (last block of batch b): softmax + argmax + copy ----
    __threadfence();  // acquire: other blocks' scores now visible
    if (w == 0) {
        volatile const float* vsc = scores;
        float lg = (lane < BM) ? logits[b * BM + lane] : -1e30f;
        float mxv = lg;
        for (int off = 32; off > 0; off >>= 1) mxv = fmaxf(mxv, __shfl_xor(mxv, off, 64));
        float e = (lane < BM) ? expf(lg - mxv) : 0.0f;
        float sum = e;
        for (int off = 32; off > 0; off >>= 1) sum += __shfl_xor(sum, off, 64);
        float sc = (lane < BM) ? (e / sum + vsc[b * BM + lane]) : -1e30f;
        int idx = lane;
        for (int off = 32; off > 0; off >>= 1) {
            const float os = __shfl_xor(sc, off, 64);
            const int   oi = __shfl_xor(idx, off, 64);
            if (os > sc || (os == sc && oi < idx)) { sc = os; idx = oi; }
        }
        if (lane == 0) {
            s_idx = idx;
            out[B * TT * 3 + b] = (float)idx;
        }
    }
    __syncthreads();
    {
        const float* src = trajs + ((size_t)b * BM + s_idx) * TT * 3;
        if (tid < TT * 3) out[b * TT * 3 + tid] = src[tid];
    }
}

extern "C" void kernel_launch(void* const* d_in, const int* in_sizes, int n_in,
                              void* d_out, int out_size, void* d_ws, size_t ws_size,
                              hipStream_t stream) {
    const float* logits = (const float*)d_in[0];
    const float* trajs  = (const float*)d_in[1];
    const float* agents = (const float*)d_in[2];
    const float* amask  = (const float*)d_in[3];
    const float* lanes  = (const float*)d_in[4];
    const float* lmask  = (const float*)d_in[5];

    const int B = in_sizes[0] / BM;  // 16
    int*   counters = (int*)d_ws;                    // first 256 B
    float* scores   = (float*)((char*)d_ws + 256);   // B*M floats
    float* out      = (float*)d_out;

    hipMemsetAsync(d_ws, 0, 256, stream);  // zero the fan-in counters
    fused_kernel<<<B * BM, 256, 0, stream>>>(logits, trajs, agents, amask,
                                             lanes, lmask, counters, scores, out, B);
}

// Round 7
// 71.043 us; speedup vs baseline: 1.2923x; 1.2923x over previous
//
#include <hip/hip_runtime.h>
#include <math.h>

#define BM 60      // modes per batch
#define TT 80      // timesteps
#define NAG 128    // agents
#define NLANES 64
#define NPTS 20
#define NLP (NLANES * NPTS)  // 1280 lane points
#define BIGOFF 1e8f

// One block of 4 waves per (b,m); wave w owns t in [20w, 20w+20).
// Both rule checks are EXISTENCE queries -> chunk-of-64 scan with exact
// early exit on the first witness (branch on ballot = wave-uniform).
// Masks folded into x coordinate (+1e8): masked points can never satisfy
// d^2 < 4 nor d^2 <= 9 — identical booleans to the reference's +1e6 penalty.
__global__ __launch_bounds__(256) void score_kernel(
    const float* __restrict__ trajs,   // (B, M, T, 3)
    const float* __restrict__ agents,  // (B, NAG, 4)
    const float* __restrict__ amask,   // (B, NAG)
    const float* __restrict__ lanes,   // (B, NLANES, NPTS, 3)
    const float* __restrict__ lmask,   // (B, NLANES)
    float* __restrict__ scores)        // (B*M,)
{
    __shared__ float s_px[NLP], s_py[NLP];   // lane points SoA (mask in x)
    __shared__ float s_ex[TT], s_ey[TT];
    __shared__ float s_j[2];
    __shared__ float s_cc[4], s_cd[4];

    const int bm   = blockIdx.x;   // b*M + m
    const int b    = bm / BM;
    const int tid  = threadIdx.x;  // 0..255
    const int w    = tid >> 6;     // wave 0..3
    const int lane = tid & 63;

    // ---- staging ----
    const float* tr = trajs + (size_t)bm * TT * 3;
    for (int i = tid; i < TT; i += 256) {
        s_ex[i] = tr[3 * i];
        s_ey[i] = tr[3 * i + 1];
    }
    const float* lbase = lanes + (size_t)b * NLP * 3;
    for (int p = tid; p < NLP; p += 256) {
        const float off = (1.0f - lmask[b * NLANES + p / NPTS]) * BIGOFF;
        s_px[p] = lbase[3 * p] + off;
        s_py[p] = lbase[3 * p + 1];
    }
    // agents: 16-byte records -> 4 registers, mask folded into x
    float ax0, ay0, ax1, ay1;
    {
        const float4* ga4 = (const float4*)(agents + (size_t)b * NAG * 4);
        const float4 a0 = ga4[lane];
        const float4 a1 = ga4[64 + lane];
        ax0 = a0.x + (1.0f - amask[b * NAG + lane]) * BIGOFF;
        ay0 = a0.y;
        ax1 = a1.x + (1.0f - amask[b * NAG + 64 + lane]) * BIGOFF;
        ay1 = a1.y;
    }
    __syncthreads();

    // comfort: jerk[t] = x[t+3]-3x[t+2]+3x[t+1]-x[t], t in [0,77)
    float jsum = 0.0f;
    if (tid < TT - 3) {
        const float jx = s_ex[tid + 3] - 3.0f * s_ex[tid + 2] + 3.0f * s_ex[tid + 1] - s_ex[tid];
        const float jy = s_ey[tid + 3] - 3.0f * s_ey[tid + 2] + 3.0f * s_ey[tid + 1] - s_ey[tid];
        jsum = sqrtf(jx * jx + jy * jy);
    }
    for (int off = 32; off > 0; off >>= 1) jsum += __shfl_xor(jsum, off, 64);
    if (w < 2 && lane == 0) s_j[w] = jsum;

    // ---- rule checks with exact early exit ----
    int ccoll = 0, cdriv = 0;
    const int t0 = w * (TT / 4);
    for (int t = t0; t < t0 + TT / 4; ++t) {
        const float ex = s_ex[t], ey = s_ey[t];  // broadcast reads

        // collision: exists agent with d^2 < 4 (2 register chunks)
        {
            float dx = ex - ax0, dy = ey - ay0;
            unsigned long long m = __ballot(fmaf(dx, dx, dy * dy) < 4.0f);
            if (m == 0ull) {
                dx = ex - ax1; dy = ey - ay1;
                m = __ballot(fmaf(dx, dx, dy * dy) < 4.0f);
            }
            ccoll += (m != 0ull) ? 1 : 0;
        }
        // drivable violation: NO lane point with d^2 <= 9 (20 LDS chunks)
        {
            unsigned long long m = 0ull;
            for (int k = 0; k < NLP / 64; ++k) {
                const int p = k * 64 + lane;
                const float dx = ex - s_px[p];
                const float dy = ey - s_py[p];
                m = __ballot(fmaf(dx, dx, dy * dy) <= 9.0f);
                if (m != 0ull) break;   // witness found: min <= 3, exact
            }
            cdriv += (m == 0ull) ? 1 : 0;
        }
    }
    if (lane == 0) { s_cc[w] = (float)ccoll; s_cd[w] = (float)cdriv; }
    __syncthreads();

    if (tid == 0) {
        const float coll = s_cc[0] + s_cc[1] + s_cc[2] + s_cc[3];
        const float driv = s_cd[0] + s_cd[1] + s_cd[2] + s_cd[3];
        const float comfort  = -((s_j[0] + s_j[1]) / (float)(TT - 3));
        const float progress = s_ex[TT - 1];
        scores[bm] = 0.1f * comfort + 0.5f * progress
                   - 1.0f * (coll / (float)TT)
                   - 0.3f * (driv / (float)TT);
    }
}

// Per-b softmax over M=60 logits, add partial scores, argmax (first-index
// tie-break like jnp.argmax), emit winning trajectory + index.
__global__ __launch_bounds__(64) void select_kernel(
    const float* __restrict__ logits,  // (B, M)
    const float* __restrict__ trajs,   // (B, M, T, 3)
    const float* __restrict__ scores,  // (B*M,)
    float* __restrict__ out,           // traj (B*T*3) then idx (B)
    int B)
{
    const int b    = blockIdx.x;
    const int lane = threadIdx.x;

    float lg = (lane < BM) ? logits[b * BM + lane] : -1e30f;
    float mx = lg;
    for (int off = 32; off > 0; off >>= 1) mx = fmaxf(mx, __shfl_xor(mx, off, 64));
    float e = (lane < BM) ? expf(lg - mx) : 0.0f;
    float sum = e;
    for (int off = 32; off > 0; off >>= 1) sum += __shfl_xor(sum, off, 64);

    float sc = (lane < BM) ? (e / sum + scores[b * BM + lane]) : -1e30f;
    int idx = lane;
    for (int off = 32; off > 0; off >>= 1) {
        float os = __shfl_xor(sc, off, 64);
        int   oi = __shfl_xor(idx, off, 64);
        if (os > sc || (os == sc && oi < idx)) { sc = os; idx = oi; }
    }
    const float* src = trajs + ((size_t)b * BM + idx) * TT * 3;
    for (int k = lane; k < TT * 3; k += 64) out[b * TT * 3 + k] = src[k];
    if (lane == 0) out[B * TT * 3 + b] = (float)idx;
}

extern "C" void kernel_launch(void* const* d_in, const int* in_sizes, int n_in,
                              void* d_out, int out_size, void* d_ws, size_t ws_size,
                              hipStream_t stream) {
    const float* logits = (const float*)d_in[0];
    const float* trajs  = (const float*)d_in[1];
    const float* agents = (const float*)d_in[2];
    const float* amask  = (const float*)d_in[3];
    const float* lanes  = (const float*)d_in[4];
    const float* lmask  = (const float*)d_in[5];

    const int B = in_sizes[0] / BM;  // 16
    float* scores = (float*)d_ws;    // B*M floats of scratch
    float* out    = (float*)d_out;

    score_kernel<<<B * BM, 256, 0, stream>>>(trajs, agents, amask, lanes, lmask, scores);
    select_kernel<<<B, 64, 0, stream>>>(logits, trajs, scores, out, B);
}